// Round 1
// baseline (469.024 us; speedup 1.0000x reference)
//
#include <hip/hip_runtime.h>
#include <cstddef>

// Problem: B=4, C=256, H=W=128, HW=16384, NPIX=65536
#define EPS_ 1e-5f

// ---------------------------------------------------------------------------
// Kernel 1: per-batch GEMM, output pixel-major:
//   f1t[(b*16384+p)*256 + o] = sum_c x[b,c,p] * W1[o,c] + b1[o]
// Tile: 128 pixels x 64 outs per block, K-chunk 32. 256 threads,
// thread = 4 contiguous px x 8 contiguous o = 32 fp32 accumulators.
// ---------------------------------------------------------------------------
__global__ __launch_bounds__(256) void k_gemm(const float* __restrict__ x,
                                              const float* __restrict__ W1,
                                              const float* __restrict__ b1,
                                              float* __restrict__ f1t)
{
  __shared__ float xs[32][128];   // [k][p]
  __shared__ float wsh[32][68];   // [k][o], padded 64->68 keeps rows 16B aligned
  const int t  = threadIdx.x;
  const int tx = t & 31, ty = t >> 5;
  const int pbase = blockIdx.x * 128;
  const int o0    = blockIdx.y * 64;
  const int b     = blockIdx.z;
  const float* xb = x + (size_t)b * 256 * 16384;

  float acc[4][8];
#pragma unroll
  for (int i = 0; i < 4; ++i)
#pragma unroll
    for (int j = 0; j < 8; ++j) acc[i][j] = 0.f;

  for (int c0 = 0; c0 < 256; c0 += 32) {
    // stage x chunk [32 c][128 p]: 1024 float4, 4 per thread, coalesced rows
    {
      const int row = t >> 3;
      const int f4  = t & 7;
#pragma unroll
      for (int jj = 0; jj < 4; ++jj) {
        const int col = (f4 + jj * 8) * 4;
        *(float4*)&xs[row][col] =
            *(const float4*)(xb + (size_t)(c0 + row) * 16384 + pbase + col);
      }
    }
    // stage W chunk transposed: wsh[k][o] = W1[o0+o][c0+k]
    {
      const int o_l = t >> 2;
      const int cc  = (t & 3) * 8;
      float4 v0 = *(const float4*)(W1 + (size_t)(o0 + o_l) * 256 + c0 + cc);
      float4 v1 = *(const float4*)(W1 + (size_t)(o0 + o_l) * 256 + c0 + cc + 4);
      wsh[cc + 0][o_l] = v0.x; wsh[cc + 1][o_l] = v0.y;
      wsh[cc + 2][o_l] = v0.z; wsh[cc + 3][o_l] = v0.w;
      wsh[cc + 4][o_l] = v1.x; wsh[cc + 5][o_l] = v1.y;
      wsh[cc + 6][o_l] = v1.z; wsh[cc + 7][o_l] = v1.w;
    }
    __syncthreads();
#pragma unroll 8
    for (int kk = 0; kk < 32; ++kk) {
      float xv[4], wv[8];
      *(float4*)&xv[0] = *(const float4*)&xs[kk][tx * 4];       // ds_read_b128
      *(float4*)&wv[0] = *(const float4*)&wsh[kk][ty * 8];      // broadcast b128
      *(float4*)&wv[4] = *(const float4*)&wsh[kk][ty * 8 + 4];
#pragma unroll
      for (int i = 0; i < 4; ++i)
#pragma unroll
        for (int j = 0; j < 8; ++j) acc[i][j] = fmaf(xv[i], wv[j], acc[i][j]);
    }
    __syncthreads();
  }

  float bb[8];
#pragma unroll
  for (int j = 0; j < 8; ++j) bb[j] = b1[o0 + ty * 8 + j];
#pragma unroll
  for (int i = 0; i < 4; ++i) {
    const int p = pbase + tx * 4 + i;
    float* dst = f1t + ((size_t)(b * 16384 + p)) * 256 + o0 + ty * 8;
    float4 s0, s1;
    s0.x = acc[i][0] + bb[0]; s0.y = acc[i][1] + bb[1];
    s0.z = acc[i][2] + bb[2]; s0.w = acc[i][3] + bb[3];
    s1.x = acc[i][4] + bb[4]; s1.y = acc[i][5] + bb[5];
    s1.z = acc[i][6] + bb[6]; s1.w = acc[i][7] + bb[7];
    *(float4*)dst = s0;
    *(float4*)(dst + 4) = s1;
  }
}

// ---------------------------------------------------------------------------
// Kernel 2: one wave per pixel (16 px per wave, 4 waves/block).
// Per pixel: L1 dist to 8 clamped neighbors (butterfly reduce over 64 lanes),
// softmax(-r*d), weighted neighbor sum + residual x, write pixel-major outT,
// and accumulate per-channel BN sums (fused stats).
// ---------------------------------------------------------------------------
__global__ __launch_bounds__(256) void k_agg(const float* __restrict__ f1t,
                                             const float* __restrict__ x,
                                             const float* __restrict__ rp,
                                             float* __restrict__ outT,
                                             float* __restrict__ s1,
                                             float* __restrict__ s2)
{
  __shared__ float ls1[256], ls2[256];
  const int t = threadIdx.x;
  const int lane = t & 63, wv = t >> 6;
  ls1[t] = 0.f; ls2[t] = 0.f;
  __syncthreads();
  const float r = rp[0];
  const int gw = blockIdx.x * 4 + wv;   // 0..4095, 16 pixels each
  float a1[4] = {0.f, 0.f, 0.f, 0.f}, a2[4] = {0.f, 0.f, 0.f, 0.f};
  const int DY[8] = {-1, -1, -1, 0, 0, 1, 1, 1};
  const int DX[8] = {-1, 0, 1, -1, 1, -1, 0, 1};

  for (int it = 0; it < 16; ++it) {
    const int p  = gw * 16 + it;
    const int b  = p >> 14;
    const int hw = p & 16383;
    const int h  = hw >> 7, w = hw & 127;
    const float4 c = *(const float4*)(f1t + (size_t)p * 256 + lane * 4);
    float nb[8][4];
    float pd[8];
#pragma unroll
    for (int k = 0; k < 8; ++k) {
      int hn = h + DY[k]; hn = hn < 0 ? 0 : (hn > 127 ? 127 : hn);
      int wn = w + DX[k]; wn = wn < 0 ? 0 : (wn > 127 ? 127 : wn);
      const int pn = (b << 14) + hn * 128 + wn;
      const float4 nv = *(const float4*)(f1t + (size_t)pn * 256 + lane * 4);
      nb[k][0] = nv.x; nb[k][1] = nv.y; nb[k][2] = nv.z; nb[k][3] = nv.w;
      pd[k] = fabsf(c.x - nv.x) + fabsf(c.y - nv.y) +
              fabsf(c.z - nv.z) + fabsf(c.w - nv.w);
    }
    // 64-lane butterfly: all lanes end with full per-neighbor distances
#pragma unroll
    for (int m = 1; m < 64; m <<= 1) {
#pragma unroll
      for (int k = 0; k < 8; ++k) pd[k] += __shfl_xor(pd[k], m, 64);
    }
    float lg[8];
    float mx = -r * pd[0];
#pragma unroll
    for (int k = 1; k < 8; ++k) mx = fmaxf(mx, -r * pd[k]);
    float sm = 0.f;
#pragma unroll
    for (int k = 0; k < 8; ++k) { lg[k] = __expf(fmaf(-r, pd[k], -mx)); sm += lg[k]; }
    const float inv = 1.f / sm;
    // residual: x is [b,c,hw] -> strided scalar loads, line-reused across it
    float o[4];
    const float* xp = x + ((size_t)b * 256 + lane * 4) * 16384 + hw;
    o[0] = xp[0]; o[1] = xp[16384]; o[2] = xp[32768]; o[3] = xp[49152];
#pragma unroll
    for (int k = 0; k < 8; ++k) {
      const float mk = lg[k] * inv;
#pragma unroll
      for (int j = 0; j < 4; ++j) o[j] = fmaf(mk, nb[k][j], o[j]);
    }
    float4 ov; ov.x = o[0]; ov.y = o[1]; ov.z = o[2]; ov.w = o[3];
    *(float4*)(outT + (size_t)p * 256 + lane * 4) = ov;
#pragma unroll
    for (int j = 0; j < 4; ++j) { a1[j] += o[j]; a2[j] += o[j] * o[j]; }
  }
  // all 4 waves share the same lane->channel map; combine in LDS, then 1
  // global atomic per channel per block (512 per block, 1024 blocks).
#pragma unroll
  for (int j = 0; j < 4; ++j) {
    atomicAdd(&ls1[lane * 4 + j], a1[j]);
    atomicAdd(&ls2[lane * 4 + j], a2[j]);
  }
  __syncthreads();
  atomicAdd(&s1[t], ls1[t]);
  atomicAdd(&s2[t], ls2[t]);
}

// ---------------------------------------------------------------------------
// Kernel 3: per-channel BN folds: scale = gamma*rsqrt(var+eps),
//           shift = beta - mean*scale   (biased var, N = 65536)
// ---------------------------------------------------------------------------
__global__ void k_stats(const float* __restrict__ s1, const float* __restrict__ s2,
                        const float* __restrict__ gamma, const float* __restrict__ beta,
                        float* __restrict__ scale, float* __restrict__ shift)
{
  const int c = threadIdx.x;
  const float n = 65536.f;
  const float mean = s1[c] / n;
  const float var  = s2[c] / n - mean * mean;
  const float sc   = gamma[c] * rsqrtf(var + EPS_);
  scale[c] = sc;
  shift[c] = beta[c] - mean * sc;
}

// ---------------------------------------------------------------------------
// Kernel 4: transpose [p][c] -> [c][p] via 64x64 LDS tile (+1 pad),
//           fused affine + LeakyReLU, coalesced float4 both sides.
// ---------------------------------------------------------------------------
__global__ __launch_bounds__(256) void k_apply(const float* __restrict__ outT,
                                               const float* __restrict__ scale,
                                               const float* __restrict__ shift,
                                               float* __restrict__ out)
{
  __shared__ float tile[64][65];
  const int t  = threadIdx.x;
  const int p0 = blockIdx.x * 64;
  const int c0 = blockIdx.y * 64;
  const int b  = blockIdx.z;
  {
    const int pl = t >> 4;          // 0..15
    const int c4 = (t & 15) * 4;
#pragma unroll
    for (int j = 0; j < 4; ++j) {
      const float4 v = *(const float4*)(
          outT + ((size_t)(b * 16384 + p0 + pl + j * 16)) * 256 + c0 + c4);
      tile[pl + j * 16][c4 + 0] = v.x;
      tile[pl + j * 16][c4 + 1] = v.y;
      tile[pl + j * 16][c4 + 2] = v.z;
      tile[pl + j * 16][c4 + 3] = v.w;
    }
  }
  __syncthreads();
  {
    const int pg  = (t & 15) * 4;   // pixel offset within tile
    const int cl0 = t >> 4;         // 0..15
#pragma unroll
    for (int j = 0; j < 4; ++j) {
      const int cl = cl0 + j * 16;
      const float sc = scale[c0 + cl], sh = shift[c0 + cl];
      float vv[4];
#pragma unroll
      for (int i = 0; i < 4; ++i) {
        const float u = fmaf(tile[pg + i][cl], sc, sh);
        vv[i] = u > 0.f ? u : 0.01f * u;
      }
      float4 v; v.x = vv[0]; v.y = vv[1]; v.z = vv[2]; v.w = vv[3];
      *(float4*)(out + ((size_t)(b * 256 + c0 + cl)) * 16384 + p0 + pg) = v;
    }
  }
}

// ---------------------------------------------------------------------------
// Workspace layout: f1t 64MB | outT 64MB | s1 1KB | s2 1KB | scale 1KB | shift 1KB
// ---------------------------------------------------------------------------
extern "C" void kernel_launch(void* const* d_in, const int* in_sizes, int n_in,
                              void* d_out, int out_size, void* d_ws, size_t ws_size,
                              hipStream_t stream)
{
  const float* x     = (const float*)d_in[0];
  const float* W1    = (const float*)d_in[1];
  const float* b1    = (const float*)d_in[2];
  const float* r     = (const float*)d_in[3];
  const float* gamma = (const float*)d_in[4];
  const float* beta  = (const float*)d_in[5];
  float* out = (float*)d_out;

  char* ws   = (char*)d_ws;
  float* f1t   = (float*)ws;                          // 64 MB
  float* outT  = (float*)(ws + ((size_t)64 << 20));   // 64 MB
  float* s1    = (float*)(ws + ((size_t)128 << 20));
  float* s2    = s1 + 256;
  float* scale = s1 + 512;
  float* shift = s1 + 768;

  // ws is poisoned 0xAA every call — zero only the atomic accumulators.
  hipMemsetAsync(s1, 0, 2 * 256 * sizeof(float), stream);

  k_gemm <<<dim3(128, 4, 4), 256, 0, stream>>>(x, W1, b1, f1t);
  k_agg  <<<dim3(1024),      256, 0, stream>>>(f1t, x, r, outT, s1, s2);
  k_stats<<<dim3(1),         256, 0, stream>>>(s1, s2, gamma, beta, scale, shift);
  k_apply<<<dim3(256, 4, 4), 256, 0, stream>>>(outT, scale, shift, out);
}